// Round 3
// baseline (14771.477 us; speedup 1.0000x reference)
//
#include <hip/hip_runtime.h>
#include <math.h>

// Problem constants
#define NB 1024      // batch
#define NH 512       // hidden
#define NT 256       // time steps
#define NCD 2        // per-step output dims

typedef unsigned short u16;
typedef __bf16 bf16x8 __attribute__((ext_vector_type(8)));
typedef float  f32x4  __attribute__((ext_vector_type(4)));
typedef unsigned int  u32x4 __attribute__((ext_vector_type(4)));

#define MFMA_BF16 __builtin_amdgcn_mfma_f32_16x16x32_bf16

__device__ __forceinline__ float sigf(float x) { return 1.0f / (1.0f + expf(-x)); }
__device__ __forceinline__ u16 f2b(float f) {   // RTNE
    union { float f; unsigned i; } v; v.f = f;
    unsigned r = v.i + 0x7fffu + ((v.i >> 16) & 1u);
    return (u16)(r >> 16);
}

// async 16B global -> LDS (L2-cacheable; used for WEIGHTS only — they are
// read-only for the whole persistent kernel, so L2 keeps them across steps).
__device__ __forceinline__ void async_cp16(const void* gptr, void* lptr) {
    __builtin_amdgcn_global_load_lds(
        (const __attribute__((address_space(1))) unsigned int*)gptr,
        (__attribute__((address_space(3))) unsigned int*)lptr,
        16, 0, 0);
}

// agent-scope (device-coherent, non-coherent-cache-bypassing) 16B load.
// Used for ALL cross-block activation traffic (h1/h2) so no cache
// invalidation is ever needed inside the persistent kernel. 4 separate
// dword atomics -> compiler tracks vmcnt per register (spill-safe waits).
__device__ __forceinline__ u32x4 aload16(const u16* p) {
    unsigned* q = (unsigned*)(void*)p;
    u32x4 v;
    v.x = __hip_atomic_load(q + 0, __ATOMIC_RELAXED, __HIP_MEMORY_SCOPE_AGENT);
    v.y = __hip_atomic_load(q + 1, __ATOMIC_RELAXED, __HIP_MEMORY_SCOPE_AGENT);
    v.z = __hip_atomic_load(q + 2, __ATOMIC_RELAXED, __HIP_MEMORY_SCOPE_AGENT);
    v.w = __hip_atomic_load(q + 3, __ATOMIC_RELAXED, __HIP_MEMORY_SCOPE_AGENT);
    return v;
}

// ---------------------------------------------------------------------------
// weight conversion fp32 -> bf16 (three 2048x512 LSTM weights)
// ---------------------------------------------------------------------------
__global__ __launch_bounds__(256) void convert3(
    const float* __restrict__ a, const float* __restrict__ b,
    const float* __restrict__ c,
    u16* __restrict__ oa, u16* __restrict__ ob, u16* __restrict__ oc)
{
    const int i = blockIdx.x * 256 + threadIdx.x;   // < 2048*512
    oa[i] = f2b(a[i]); ob[i] = f2b(b[i]); oc[i] = f2b(c[i]);
}

__global__ __launch_bounds__(256) void convw1(
    const float* __restrict__ a, u16* __restrict__ o)
{
    const int i = blockIdx.x * 256 + threadIdx.x;   // < 256*512
    o[i] = f2b(a[i]);
}

__global__ __launch_bounds__(256) void bsum_k(
    const float* __restrict__ bi1, const float* __restrict__ bh1,
    const float* __restrict__ bi2, const float* __restrict__ bh2,
    float* __restrict__ o1, float* __restrict__ o2)
{
    const int i = blockIdx.x * 256 + threadIdx.x;   // < 2048
    o1[i] = bi1[i] + bh1[i];
    o2[i] = bi2[i] + bh2[i];
}

__global__ __launch_bounds__(512) void zero_bar(unsigned* __restrict__ b)
{
    b[threadIdx.x] = 0u;    // 32 grps x 16-word spacing
}

// ---------------------------------------------------------------------------
// init: [h0 | c0] = z @ W_proj^T + b_proj ; h0 (bf16) -> h1,h2 ; c0 (f32)
// ---------------------------------------------------------------------------
__global__ __launch_bounds__(256) void init_kernel(
    const float* __restrict__ zp, const float* __restrict__ zs,
    const float* __restrict__ zst, const float* __restrict__ Wp,
    const float* __restrict__ bp,
    u16* __restrict__ h1, float* __restrict__ c1,
    u16* __restrict__ h2, float* __restrict__ c2)
{
    __shared__ float z[4][256];
    const int tid = threadIdx.x;
    const int b0  = blockIdx.x * 4;
    for (int i = tid; i < 4 * 256; i += 256) {
        const int bb = i >> 8, k = i & 255;
        float v;
        if (k < 64)       v = zp [(b0 + bb) * 64  + k];
        else if (k < 128) v = zs [(b0 + bb) * 64  + (k - 64)];
        else              v = zst[(b0 + bb) * 128 + (k - 128)];
        z[bb][k] = v;
    }
    __syncthreads();
    for (int rt = 0; rt < 4; ++rt) {
        const int r = rt * 256 + tid;          // 0..1023
        const float bias = bp[r];
        float a0 = bias, a1 = bias, a2 = bias, a3 = bias;
        for (int k = 0; k < 256; ++k) {
            const float w = Wp[r * 256 + k];
            a0 += z[0][k] * w; a1 += z[1][k] * w;
            a2 += z[2][k] * w; a3 += z[3][k] * w;
        }
        const float acc[4] = {a0, a1, a2, a3};
        for (int bb = 0; bb < 4; ++bb) {
            const int b = b0 + bb;
            if (r < NH) {
                h1[b * NH + r] = f2b(acc[bb]);
                h2[b * NH + r] = f2b(acc[bb]);
            } else {
                c1[b * NH + r - NH] = acc[bb];
                c2[b * NH + r - NH] = acc[bb];
            }
        }
    }
}

// ---------------------------------------------------------------------------
// PERSISTENT kernel: the entire T=256 loop in ONE dispatch.
//  - grid 512 x 512 threads = exactly 2 blocks/CU on 256 CUs (co-resident:
//    LDS 60KB -> 2/CU, __launch_bounds__(512,4) caps VGPR <= 128).
//  - batch groups (grp = 32 rows) never mix -> only per-grp 16-block
//    barriers, via relaxed agent atomics. NO fences -> L2 is never
//    invalidated -> weight slices stay L2-resident for all 256 steps.
//  - all cross-block h1/h2 traffic via agent-scope loads/stores (LLC),
//    weights via async_cp16 (L2).
//  - c1/c2 register-resident; per-step scalars hoisted out of the loop.
// wv<4 in-loop wait = vmcnt(6): steady-state outstanding is exactly
// {W(m+1) 2 x gload_lds, next-A 4 x dword} = 6 -> wait is free but forces
// macro-m W/A retirement even if the implicit-wait chain is perturbed.
// ---------------------------------------------------------------------------
__global__ __launch_bounds__(512, 4) void decoder_persistent(
    const u16* __restrict__ Whh1b, const u16* __restrict__ Wih2b,
    const u16* __restrict__ Whh2b, const u16* __restrict__ Wo1b,
    const float* __restrict__ bs1, const float* __restrict__ bs2,
    const float* __restrict__ Wih1, const float* __restrict__ bo1,
    const float* __restrict__ Wo2, const float* __restrict__ bo2,
    const float* __restrict__ c1i, const float* __restrict__ c2i,
    float* __restrict__ outp,
    u16* h1A, u16* h1B, u16* h2A, u16* h2B,
    unsigned* bar)
{
    __shared__ __align__(16) char smem[61440];   // phaseB: 3 x (As 4KB|Ws 16KB)
    float* eg  = (float*)smem;                   // lstm epilogue alias
    float* red = (float*)(smem + 40960);         // phaseA reduce scratch (2KB)

    const int tid  = threadIdx.x;
    const int lane = tid & 63;
    const int wv   = tid >> 6;          // 0..7
    const int g    = wv & 3;            // gate (phaseB)
    const int mh   = wv >> 2;           // batch half (phaseB)
    const int l15  = lane & 15;
    const int q    = lane >> 4;         // 0..3
    const int bx   = blockIdx.x;
    const int ut   = (bx & 7) * 2 + ((bx >> 3) & 1);  // 0..15 (XCD-confined)
    const int grp  = bx >> 4;                          // 0..31
    const int b0   = grp * 32;
    const int u0   = ut * 32;

    // staging descriptors (identical derivation to the verified R14 kernel)
    int goffW0, goffW1, goffA = 0, goffO[4];
    {
        const int c0 = (wv * 2) * 64 + lane;
        const int w0r = c0 >> 3;
        goffW0 = ((w0r >> 5) * NH + u0 + (w0r & 31)) * NH + (((c0 & 7) ^ (w0r & 7)) * 8);
        const int c1x = (wv * 2 + 1) * 64 + lane;
        const int w1r = c1x >> 3;
        goffW1 = ((w1r >> 5) * NH + u0 + (w1r & 31)) * NH + (((c1x & 7) ^ (w1r & 7)) * 8);
        if (wv < 4) {
            const int ca = wv * 64 + lane;
            const int ar = ca >> 3;
            goffA = (b0 + ar) * NH + (((ca & 7) ^ (ar & 7)) * 8);
        }
#pragma unroll
        for (int i = 0; i < 4; ++i) {
            const int cidx = (wv * 4 + i) * 64 + lane;
            const int row  = cidx >> 3;
            const int kc   = (cidx & 7) ^ (row & 7);
            goffO[i] = row * NH + kc * 8;
        }
    }

    // ---- loop-invariant scalars (loaded once for all 256 steps) ----------
    const int u_e  = tid & 31;
    const int bq_e = tid >> 5;
    const int ug_e = u0 + u_e;
    float bs1r[4], bs2r[4], wx0[4], wx1[4];
#pragma unroll
    for (int g4 = 0; g4 < 4; ++g4) {
        bs1r[g4] = bs1[g4 * NH + ug_e];
        bs2r[g4] = bs2[g4 * NH + ug_e];
        wx0[g4]  = Wih1[(g4 * NH + ug_e) * 2 + 0];
        wx1[g4]  = Wih1[(g4 * NH + ug_e) * 2 + 1];
    }
    float c1r[2], c2r[2];                        // cell state in REGISTERS
    c1r[0] = c1i[(size_t)(b0 + bq_e * 2 + 0) * NH + ug_e];
    c1r[1] = c1i[(size_t)(b0 + bq_e * 2 + 1) * NH + ug_e];
    c2r[0] = c2i[(size_t)(b0 + bq_e * 2 + 0) * NH + ug_e];
    c2r[1] = c2i[(size_t)(b0 + bq_e * 2 + 1) * NH + ug_e];
    float bo1n[2], w20[2], w21[2];
#pragma unroll
    for (int ni = 0; ni < 2; ++ni) {
        const int n = wv * 32 + ni * 16 + l15;
        bo1n[ni] = bo1[n]; w20[ni] = Wo2[n]; w21[ni] = Wo2[256 + n];
    }
    const float bo2c0 = bo2[0], bo2c1 = bo2[1];

    u16 *h1c = h1A, *h1n = h1B, *h2c = h2A, *h2n = h2B;   // in-kernel ping-pong
    unsigned  bar_target = 0;
    unsigned* mybar = bar + grp * 16;            // 64B spacing per grp

    u32x4 rO0, rO1, rB0, rB1;                    // A-tile register staging (wv<4)

    auto issueWB = [&](const u16* Wp, int m, int bi) {   // W staging (all waves)
        const int k0 = (m & 7) * 64;
        char* base = smem + bi * 20480;
        async_cp16((const void*)(Wp + goffW0 + k0), (void*)(base + 4096 + (wv * 2) * 1024));
        async_cp16((const void*)(Wp + goffW1 + k0), (void*)(base + 4096 + (wv * 2 + 1) * 1024));
    };
    auto awrite = [&](char* base, u32x4 v) {     // A-tile LDS write (wv<4)
        *(u32x4*)(base + wv * 1024 + lane * 16) = v;
    };
    auto mstep = [&](const char* bA, f32x4* acc) {       // one K=64 macro
        const char* bW = bA + 4096;
#pragma unroll
        for (int khi = 0; khi < 2; ++khi) {
            bf16x8 bfr[2];
#pragma unroll
            for (int ni = 0; ni < 2; ++ni) {
                const int wrow = g * 32 + ni * 16 + l15;
                const int j = (khi * 4 + q) ^ (wrow & 7);
                bfr[ni] = *(const bf16x8*)(bW + wrow * 128 + j * 16);
            }
            const int row = mh * 16 + l15;
            const int j = (khi * 4 + q) ^ (row & 7);
            const bf16x8 av = *(const bf16x8*)(bA + row * 128 + j * 16);
            acc[0] = MFMA_BF16(av, bfr[0], acc[0], 0, 0, 0);
            acc[1] = MFMA_BF16(av, bfr[1], acc[1], 0, 0, 0);
        }
    };
    // per-grp 16-block barrier. __syncthreads drains vmcnt(0) -> all agent
    // h-stores are at the coherence point before the leader's arrive.
    auto grpbar = [&]() {
        bar_target += 16;
        __syncthreads();
        if (tid == 0) {
            __hip_atomic_fetch_add(mybar, 1u, __ATOMIC_RELAXED, __HIP_MEMORY_SCOPE_AGENT);
            int guard = 0;
            while (__hip_atomic_load(mybar, __ATOMIC_RELAXED, __HIP_MEMORY_SCOPE_AGENT)
                       < bar_target && ++guard < (1 << 16)) {
                __builtin_amdgcn_s_sleep(1);
            }
        }
        __syncthreads();
    };
    // fused LSTM cell pointwise + paired (u32) agent store of h
    auto cellEp = [&](f32x4* acc, const float* bsr, float* cr, u16* hdst,
                      const float* rx) {
        __syncthreads();                         // K-loop LDS reads done
#pragma unroll
        for (int ni = 0; ni < 2; ++ni)
#pragma unroll
            for (int r = 0; r < 4; ++r)
                eg[(g * 32 + mh * 16 + q * 4 + r) * 33 + ni * 16 + l15] = acc[ni][r];
        __syncthreads();
#pragma unroll
        for (int jj = 0; jj < 2; ++jj) {
            const int bl = bq_e * 2 + jj;
            const int b  = b0 + bl;
            float gv[4];
#pragma unroll
            for (int g4 = 0; g4 < 4; ++g4) {
                gv[g4] = eg[(g4 * 32 + bl) * 33 + u_e] + bsr[g4];
                if (rx) gv[g4] += rx[jj * 2 + 0] * wx0[g4] + rx[jj * 2 + 1] * wx1[g4];
            }
            const float iv = sigf(gv[0]);
            const float fv = sigf(gv[1]);
            const float gg = tanhf(gv[2]);
            const float ov = sigf(gv[3]);
            const float cn = fv * cr[jj] + iv * gg;
            cr[jj] = cn;
            const unsigned hb = (unsigned)f2b(ov * tanhf(cn));
            const unsigned pr = (unsigned)__shfl_xor((int)hb, 1, 64);
            if (!(u_e & 1))
                __hip_atomic_store((unsigned*)(void*)(hdst + (size_t)b * NH + ug_e),
                                   hb | (pr << 16),
                                   __ATOMIC_RELAXED, __HIP_MEMORY_SCOPE_AGENT);
        }
    };

    for (int t = 0; t <= NT; ++t) {
        const bool do_l = (t < NT);
        // step-start prefetch: A(0) tiles for phaseA (h2) and phaseB (h1)
        if (wv < 4) {
            if (t > 0) rO0 = aload16(h2c + goffA);
            if (do_l)  rB0 = aload16(h1c + goffA);
        }
        if (do_l) issueWB(Whh1b, 0, 2);          // pre-issue phaseB W(0)->buf2

        float r_x[4] = {0.f, 0.f, 0.f, 0.f};

        // ---------------- phase A: out(t-1), redundant per block -----------
        if (t > 0) {
            f32x4 acc_o[2][2];
#pragma unroll
            for (int mi = 0; mi < 2; ++mi)
#pragma unroll
                for (int ni = 0; ni < 2; ++ni)
                    acc_o[mi][ni] = (f32x4){0.f, 0.f, 0.f, 0.f};

            for (int kk = 0; kk < 8; ++kk) {
                __syncthreads();                 // prev macro's readers done
#pragma unroll
                for (int i = 0; i < 4; ++i)
                    async_cp16((const void*)(Wo1b + goffO[i] + kk * 64),
                               (void*)(smem + ((wv * 4 + i) << 10)));
                char* aBase = smem + 32768 + (kk & 1) * 4096;
                if (wv < 4) awrite(aBase, (kk & 1) ? rO1 : rO0);
                asm volatile("s_waitcnt vmcnt(0) lgkmcnt(0)" ::: "memory");
                __builtin_amdgcn_s_barrier();
                if (wv < 4 && kk + 1 < 8) {      // prefetch next A under compute
                    if ((kk + 1) & 1) rO1 = aload16(h2c + goffA + (kk + 1) * 64);
                    else              rO0 = aload16(h2c + goffA + (kk + 1) * 64);
                }
#pragma unroll
                for (int kh = 0; kh < 2; ++kh) {
                    bf16x8 bfr[2], av[2];
#pragma unroll
                    for (int ni = 0; ni < 2; ++ni) {
                        const int wrow = wv * 32 + ni * 16 + l15;
                        const int j = (kh * 4 + q) ^ (wrow & 7);
                        bfr[ni] = *(const bf16x8*)(smem + wrow * 128 + j * 16);
                    }
#pragma unroll
                    for (int mi = 0; mi < 2; ++mi) {
                        const int row = mi * 16 + l15;
                        const int j = (kh * 4 + q) ^ (row & 7);
                        av[mi] = *(const bf16x8*)(aBase + row * 128 + j * 16);
                    }
#pragma unroll
                    for (int mi = 0; mi < 2; ++mi)
#pragma unroll
                        for (int ni = 0; ni < 2; ++ni)
                            acc_o[mi][ni] = MFMA_BF16(av[mi], bfr[ni], acc_o[mi][ni], 0, 0, 0);
                }
            }
            // epilogue: relu(pre1+bo1) * Wo2, reduce over n
            float pa[2][4], pb[2][4];
#pragma unroll
            for (int mi = 0; mi < 2; ++mi)
#pragma unroll
                for (int r = 0; r < 4; ++r) {
                    const float s0 = fmaxf(acc_o[mi][0][r] + bo1n[0], 0.f);
                    const float s1 = fmaxf(acc_o[mi][1][r] + bo1n[1], 0.f);
                    pa[mi][r] = s0 * w20[0] + s1 * w20[1];
                    pb[mi][r] = s0 * w21[0] + s1 * w21[1];
                }
#pragma unroll
            for (int off = 1; off < 16; off <<= 1)
#pragma unroll
                for (int mi = 0; mi < 2; ++mi)
#pragma unroll
                    for (int r = 0; r < 4; ++r) {
                        pa[mi][r] += __shfl_xor(pa[mi][r], off, 64);
                        pb[mi][r] += __shfl_xor(pb[mi][r], off, 64);
                    }
            if (l15 == 0) {
#pragma unroll
                for (int mi = 0; mi < 2; ++mi)
#pragma unroll
                    for (int r = 0; r < 4; ++r) {
                        const int m = mi * 16 + q * 4 + r;
                        red[m * 16 + wv * 2 + 0] = pa[mi][r];
                        red[m * 16 + wv * 2 + 1] = pb[mi][r];
                    }
            }
            __syncthreads();
            if (ut == 0 && tid < 64) {          // one writer tile per grp
                const int bl = tid >> 1, cc = tid & 1;
                float y = cc ? bo2c1 : bo2c0;
#pragma unroll
                for (int w8 = 0; w8 < 8; ++w8) y += red[bl * 16 + w8 * 2 + cc];
                outp[(size_t)(b0 + bl) * (NT * NCD) + (t - 1) * NCD + cc] = y;
            }
            if (do_l) {                         // everyone grabs its own rows
#pragma unroll
                for (int jj = 0; jj < 2; ++jj)
#pragma unroll
                    for (int cc = 0; cc < 2; ++cc) {
                        float y = cc ? bo2c1 : bo2c0;
#pragma unroll
                        for (int w8 = 0; w8 < 8; ++w8)
                            y += red[(bq_e * 2 + jj) * 16 + w8 * 2 + cc];
                        r_x[jj * 2 + cc] = y;
                    }
            }
            __syncthreads();                    // red reads done before reuse
        }
        if (!do_l) break;                       // t==NT: final out written

        // ---------------- phase B: lstm1 K-loop (buf order 2,0,1,...) ------
        {
            f32x4 acc[2];
            acc[0] = (f32x4){0.f, 0.f, 0.f, 0.f};
            acc[1] = (f32x4){0.f, 0.f, 0.f, 0.f};
            if (wv < 4) rB1 = aload16(h1c + goffA + 64);
            issueWB(Whh1b, 1, 0);
            if (wv < 4) {
                awrite(smem + 2 * 20480, rB0);  // A(0)->buf2
                awrite(smem + 0 * 20480, rB1);  // A(1)->buf0 (drains W(0) too)
                rB0 = aload16(h1c + goffA + 128);
            }
            int ci = 2;
            for (int m = 0; m < 8; ++m) {
                if (m + 1 < 8) {
                    if (wv < 4) asm volatile("s_waitcnt vmcnt(6) lgkmcnt(0)" ::: "memory");
                    else        asm volatile("s_waitcnt vmcnt(2)" ::: "memory");
                } else {
                    asm volatile("s_waitcnt vmcnt(0) lgkmcnt(0)" ::: "memory");
                }
                __builtin_amdgcn_s_barrier();
                if (m + 2 < 8) {
                    int bi = ci + 2; if (bi >= 3) bi -= 3;
                    if (wv < 4) awrite(smem + bi * 20480, (m & 1) ? rB1 : rB0);
                    issueWB(Whh1b, m + 2, bi);
                    if (wv < 4 && m + 3 < 8) {
                        if (m & 1) rB0 = aload16(h1c + goffA + (m + 3) * 64);
                        else       rB1 = aload16(h1c + goffA + (m + 3) * 64);
                    }
                }
                mstep(smem + ci * 20480, acc);
                ++ci; if (ci == 3) ci = 0;
            }
            cellEp(acc, bs1r, c1r, h1n, r_x);   // -> h1(t), c1 in regs
        }
        grpbar();                               // h1(t) visible to grp peers

        // ---------------- lstm2: h1(t)@Wih2 + h2(t-1)@Whh2 -----------------
        {
            f32x4 acc[2];
            acc[0] = (f32x4){0.f, 0.f, 0.f, 0.f};
            acc[1] = (f32x4){0.f, 0.f, 0.f, 0.f};
            // ordering: aload -> issueWB(0) -> aload -> issueWB(1) so the
            // awrite(buf1, rB1) implicit wait drains W(0) before m=0 barrier.
            if (wv < 4) rB0 = aload16(h1n + goffA);
            issueWB(Wih2b, 0, 0);
            if (wv < 4) rB1 = aload16(h1n + goffA + 64);
            issueWB(Wih2b, 1, 1);
            if (wv < 4) {
                awrite(smem + 0 * 20480, rB0);
                awrite(smem + 1 * 20480, rB1);  // drains W(0)
                rB0 = aload16(h1n + goffA + 128);
            }
            int ci = 0;
            for (int m = 0; m < 16; ++m) {
                if (m + 1 < 16) {
                    if (wv < 4) asm volatile("s_waitcnt vmcnt(6) lgkmcnt(0)" ::: "memory");
                    else        asm volatile("s_waitcnt vmcnt(2)" ::: "memory");
                } else {
                    asm volatile("s_waitcnt vmcnt(0) lgkmcnt(0)" ::: "memory");
                }
                __builtin_amdgcn_s_barrier();
                if (m + 2 < 16) {
                    int bi = ci + 2; if (bi >= 3) bi -= 3;
                    if (wv < 4) awrite(smem + bi * 20480, (m & 1) ? rB1 : rB0);
                    issueWB((m + 2 < 8) ? Wih2b : Whh2b, m + 2, bi);
                    if (wv < 4 && m + 3 < 16) {
                        const u16* Ap = (m + 3 < 8) ? h1n : h2c;
                        const int k0 = ((m + 3) & 7) * 64;
                        if (m & 1) rB0 = aload16(Ap + goffA + k0);
                        else       rB1 = aload16(Ap + goffA + k0);
                    }
                }
                mstep(smem + ci * 20480, acc);
                ++ci; if (ci == 3) ci = 0;
            }
            cellEp(acc, bs2r, c2r, h2n, (const float*)0);  // -> h2(t), c2 regs
        }
        grpbar();                               // h2(t) visible to grp peers

        { u16* tp = h1c; h1c = h1n; h1n = tp; tp = h2c; h2c = h2n; h2n = tp; }
    }
}

// ---------------------------------------------------------------------------
extern "C" void kernel_launch(void* const* d_in, const int* in_sizes, int n_in,
                              void* d_out, int out_size, void* d_ws, size_t ws_size,
                              hipStream_t stream)
{
    const float* zp   = (const float*)d_in[0];
    const float* zsk  = (const float*)d_in[1];
    const float* zst  = (const float*)d_in[2];
    const float* Wp   = (const float*)d_in[3];
    const float* bp   = (const float*)d_in[4];
    const float* Wih1 = (const float*)d_in[5];
    const float* Whh1 = (const float*)d_in[6];
    const float* bih1 = (const float*)d_in[7];
    const float* bhh1 = (const float*)d_in[8];
    const float* Wih2 = (const float*)d_in[9];
    const float* Whh2 = (const float*)d_in[10];
    const float* bih2 = (const float*)d_in[11];
    const float* bhh2 = (const float*)d_in[12];
    const float* Wo1  = (const float*)d_in[13];
    const float* bo1  = (const float*)d_in[14];
    const float* Wo2  = (const float*)d_in[15];
    const float* bo2  = (const float*)d_in[16];

    const size_t BH = (size_t)NB * NH;          // 524288
    u16*   h1a   = (u16*)d_ws;
    u16*   h1b   = h1a + BH;
    u16*   h2a   = h1b + BH;
    u16*   h2b   = h2a + BH;
    float* c1    = (float*)(h2b + BH);
    float* c2    = c1 + BH;
    float* bs1   = c2 + BH;                     // 2048
    float* bs2   = bs1 + 2048;                  // 2048
    u16*   Wo1b  = (u16*)(bs2 + 2048);          // 131072 u16
    u16*   Whh1b = Wo1b + 131072;               // 1048576 each
    u16*   Wih2b = Whh1b + 1048576;
    u16*   Whh2b = Wih2b + 1048576;
    unsigned* bar = (unsigned*)(Whh2b + 1048576);   // 512 u32 (32 grps x 16)
    // total ~14.3 MB of d_ws

    convert3<<<(2048 * 512) / 256, 256, 0, stream>>>(Whh1, Wih2, Whh2, Whh1b, Wih2b, Whh2b);
    convw1<<<(256 * 512) / 256, 256, 0, stream>>>(Wo1, Wo1b);
    bsum_k<<<2048 / 256, 256, 0, stream>>>(bih1, bhh1, bih2, bhh2, bs1, bs2);
    init_kernel<<<NB / 4, 256, 0, stream>>>(zp, zsk, zst, Wp, bp, h1a, c1, h2a, c2);
    zero_bar<<<1, 512, 0, stream>>>(bar);

    decoder_persistent<<<512, 512, 0, stream>>>(
        Whh1b, Wih2b, Whh2b, Wo1b, bs1, bs2, Wih1, bo1, Wo2, bo2,
        c1, c2, (float*)d_out, h1a, h1b, h2a, h2b, bar);
}